// Round 18
// baseline (38.854 us; speedup 1.0000x reference)
//
#include <hip/hip_runtime.h>
#include <math.h>

#define NB 2048
#define ND 784
#define NK 128
#define NSTEP 98           // K = 4d+c -> 3136 = 98 k-steps of 32
#define SPK 25             // k-steps per kc quarter (last 2 of kc=3 skipped)

typedef __attribute__((ext_vector_type(8))) short short8;
typedef __attribute__((ext_vector_type(4))) float f32x4;

// ws float offsets (no partials anymore):
#define OFF_LW   0
#define OFF_BH   128
#define N_B_F    (NSTEP * 8 * 64 * 4)     // 200,704 float slots per table
#define OFF_BL   (OFF_BH + N_B_F)
// total ~1.6 MB

__device__ inline ushort f2bf(float f) {   // round-to-nearest-even f32->bf16
  uint u = __float_as_uint(f);
  return (ushort)((u + 0x7FFFu + ((u >> 16) & 1u)) >> 16);
}

// B-prep, COALESCED (validated R16/R17): thread g -> (n = g/392, dpair),
// float2 reads, fragment-linear hi/lo B, log w.
__global__ __launch_bounds__(256) void k_prep(
    const float* __restrict__ w, const float* __restrict__ mu,
    const float* __restrict__ cov, float* __restrict__ ws) {
  int g = blockIdx.x * 256 + threadIdx.x;   // 0..50175
  if (g < NK) ws[OFF_LW + g] = logf(w[g]);
  int n  = g / 392;
  int dp = g - n * 392;
  int d0 = dp * 2;
  float2 cv = *(const float2*)(cov + (size_t)n * ND + d0);
  float2 mv = *(const float2*)(mu  + (size_t)n * ND + d0);
  float va[8];
  va[0] = -0.5f / cv.x;
  va[1] = mv.x / cv.x;
  va[2] = -mv.x * mv.x * 0.5f / cv.x - 0.5f * logf(cv.x);
  va[3] = 0.f;
  va[4] = -0.5f / cv.y;
  va[5] = mv.y / cv.y;
  va[6] = -mv.y * mv.y * 0.5f / cv.y - 0.5f * logf(cv.y);
  va[7] = 0.f;
  ushort hi[8], lo[8];
#pragma unroll
  for (int j = 0; j < 8; j++) {
    ushort h = f2bf(va[j]);
    hi[j] = h;
    lo[j] = f2bf(va[j] - __uint_as_float(((uint)h) << 16));
  }
  uint4 vh, vl;
  vh.x = (uint)hi[0] | ((uint)hi[1] << 16);
  vh.y = (uint)hi[2] | ((uint)hi[3] << 16);
  vh.z = (uint)hi[4] | ((uint)hi[5] << 16);
  vh.w = (uint)hi[6] | ((uint)hi[7] << 16);
  vl.x = (uint)lo[0] | ((uint)lo[1] << 16);
  vl.y = (uint)lo[2] | ((uint)lo[3] << 16);
  vl.z = (uint)lo[4] | ((uint)lo[5] << 16);
  vl.w = (uint)lo[6] | ((uint)lo[7] << 16);
  int ks = dp >> 2, lg = dp & 3, nt = n >> 4, nl = n & 15;
  int fid = ks * 8 + nt;
  int lp  = lg * 16 + nl;
  ((uint4*)(ws + OFF_BH))[fid * 64 + lp] = vh;
  ((uint4*)(ws + OFF_BL))[fid * 64 + lp] = vl;
}

// FUSED GEMM + softmax. 128 blocks x 1024 threads (16 waves).
// Wave W: kc = W>>2 (K-quarter), ng = W&3 (32-col group, nt = ng*2, ng*2+1).
// All waves share the block's 16 rows. K-loop: batched B/x/m loads -> convert
// -> 6 MFMAs (validated R15 math). Then intra-block split-K reduction via LDS
// + per-row 64-lane LSE (validated k_final math). No global partials, no
// fences, no atomics.
__global__ __launch_bounds__(1024, 1) void k_fused(
    const float* __restrict__ data, const float* __restrict__ mask,
    const float* __restrict__ ws, float* __restrict__ out) {
  __shared__ float lds[4 * 16 * 132];   // 33792 B, [kc][row][col(+pad)]

  const short8* Bh = (const short8*)(ws + OFF_BH);
  const short8* Bl = (const short8*)(ws + OFF_BL);

  int W  = threadIdx.x >> 6;
  int l  = threadIdx.x & 63;
  int ng = W & 3;
  int kc = W >> 2;
  int r0 = blockIdx.x << 4;
  int rowA = r0 + (l & 15);
  int g2   = (l >> 4) << 1;
  int n0   = ng * 2;          // first nt of this wave

  const float* dp = data + (size_t)rowA * ND + g2;
  const float* mp = mask + (size_t)rowA * ND + g2;

  f32x4 acc[2];
  acc[0] = (f32x4){0.f, 0.f, 0.f, 0.f};
  acc[1] = (f32x4){0.f, 0.f, 0.f, 0.f};

#pragma unroll 5
  for (int s = 0; s < SPK; s++) {
    int ks = kc * SPK + s;
    if (ks < NSTEP) {
      // batched loads (one latency window; 16 waves/CU hide it)
      const short8* bh = Bh + ((size_t)(ks * 8) + n0) * 64 + l;
      const short8* bl = Bl + ((size_t)(ks * 8) + n0) * 64 + l;
      short8 b_h0 = bh[0], b_h1 = bh[64];
      short8 b_l0 = bl[0], b_l1 = bl[64];
      float2 x = *(const float2*)(dp + ks * 8);
      float2 m = *(const float2*)(mp + ks * 8);

      float mx0 = m.x * x.x, mq0 = mx0 * x.x;
      float mx1 = m.y * x.y, mq1 = mx1 * x.y;
      ushort h_q0 = f2bf(mq0), h_x0 = f2bf(mx0);
      ushort h_q1 = f2bf(mq1), h_x1 = f2bf(mx1);
      ushort h_m0 = (ushort)(__float_as_uint(m.x) >> 16);  // exact: m in {0,1}
      ushort h_m1 = (ushort)(__float_as_uint(m.y) >> 16);
      float r_q0 = mq0 - __uint_as_float(((uint)h_q0) << 16);
      float r_x0 = mx0 - __uint_as_float(((uint)h_x0) << 16);
      float r_q1 = mq1 - __uint_as_float(((uint)h_q1) << 16);
      float r_x1 = mx1 - __uint_as_float(((uint)h_x1) << 16);

      short8 a_h, a_l;
      a_h[0] = (short)h_q0;       a_h[1] = (short)h_x0;
      a_h[2] = (short)h_m0;       a_h[3] = 0;
      a_h[4] = (short)h_q1;       a_h[5] = (short)h_x1;
      a_h[6] = (short)h_m1;       a_h[7] = 0;
      a_l[0] = (short)f2bf(r_q0); a_l[1] = (short)f2bf(r_x0);
      a_l[2] = 0;                 a_l[3] = 0;
      a_l[4] = (short)f2bf(r_q1); a_l[5] = (short)f2bf(r_x1);
      a_l[6] = 0;                 a_l[7] = 0;

      acc[0] = __builtin_amdgcn_mfma_f32_16x16x32_bf16(a_h, b_h0, acc[0], 0, 0, 0);
      acc[0] = __builtin_amdgcn_mfma_f32_16x16x32_bf16(a_h, b_l0, acc[0], 0, 0, 0);
      acc[0] = __builtin_amdgcn_mfma_f32_16x16x32_bf16(a_l, b_h0, acc[0], 0, 0, 0);
      acc[1] = __builtin_amdgcn_mfma_f32_16x16x32_bf16(a_h, b_h1, acc[1], 0, 0, 0);
      acc[1] = __builtin_amdgcn_mfma_f32_16x16x32_bf16(a_h, b_l1, acc[1], 0, 0, 0);
      acc[1] = __builtin_amdgcn_mfma_f32_16x16x32_bf16(a_l, b_h1, acc[1], 0, 0, 0);
    }
  }

  // drop acc into LDS: [kc][row][col], disjoint per wave
#pragma unroll
  for (int t = 0; t < 2; t++)
#pragma unroll
    for (int r = 0; r < 4; r++) {
      int row = ((l >> 4) << 2) + r;
      int col = (n0 + t) * 16 + (l & 15);
      lds[(kc * 16 + row) * 132 + col] = acc[t][r];
    }
  __syncthreads();

  // wave W reduces row W: 2 cols/lane (2l, 2l+1), 4 kc slices
  float2 s2 = make_float2(0.f, 0.f);
#pragma unroll
  for (int c = 0; c < 4; c++) {
    float2 v = *(const float2*)&lds[(c * 16 + W) * 132 + 2 * l];
    s2.x += v.x; s2.y += v.y;
  }
  float2 lw = ((const float2*)(ws + OFF_LW))[l];
  s2.x += lw.x; s2.y += lw.y;
  if (isnan(s2.x)) s2.x = 0.f;
  if (isnan(s2.y)) s2.y = 0.f;

  float mx = fmaxf(s2.x, s2.y);
#pragma unroll
  for (int off = 32; off; off >>= 1) mx = fmaxf(mx, __shfl_xor(mx, off));
  float sum = expf(s2.x - mx) + expf(s2.y - mx) + 2e-8f;   // ref's +1e-8/elem
#pragma unroll
  for (int off = 32; off; off >>= 1) sum += __shfl_xor(sum, off);
  float lse = logf(sum) + mx;
  float2 o = make_float2(expf(s2.x - lse), expf(s2.y - lse));
  ((float2*)out)[(size_t)(r0 + W) * 64 + l] = o;
}

extern "C" void kernel_launch(void* const* d_in, const int* in_sizes, int n_in,
                              void* d_out, int out_size, void* d_ws, size_t ws_size,
                              hipStream_t stream) {
  const float* data = (const float*)d_in[0];
  const float* mask = (const float*)d_in[1];
  const float* wts  = (const float*)d_in[2];
  const float* mu   = (const float*)d_in[3];
  const float* cov  = (const float*)d_in[4];
  float* ws  = (float*)d_ws;
  float* out = (float*)d_out;

  k_prep<<<196, 256, 0, stream>>>(wts, mu, cov, ws);
  k_fused<<<NB / 16, 1024, 0, stream>>>(data, mask, ws, out);
}

// Round 19
// 32.477 us; speedup vs baseline: 1.1964x; 1.1964x over previous
//
#include <hip/hip_runtime.h>
#include <math.h>

#define NB 2048
#define ND 784
#define NK 128
#define NSTEP 98           // K = 4d+c -> 3136 = 98 k-steps of 32
#define KSPLIT 14          // K-chunks -> partials
#define SPK 7              // k-steps per chunk
#define MT 64              // rows per k_mm block (4 waves x 16 rows)
#define NHALF 4            // N-split: each wave does 2 nt = 32 cols

typedef __attribute__((ext_vector_type(8))) short short8;
typedef __attribute__((ext_vector_type(4))) float f32x4;

// ws float offsets:
#define OFF_LW   0
#define OFF_PART 128
#define N_PART   (KSPLIT * NB * NK)       // 3,670,016 floats (14.7 MB)
#define OFF_BH   (OFF_PART + N_PART)
#define N_B_F    (NSTEP * 8 * 64 * 4)     // 200,704 float slots per table
#define OFF_BL   (OFF_BH + N_B_F)

__device__ inline ushort f2bf(float f) {   // round-to-nearest-even f32->bf16
  uint u = __float_as_uint(f);
  return (ushort)((u + 0x7FFFu + ((u >> 16) & 1u)) >> 16);
}

// B-prep, COALESCED (validated R16/R17): thread g -> (n = g/392, dpair),
// float2 reads, fragment-linear hi/lo B, log w.
__global__ __launch_bounds__(256) void k_prep(
    const float* __restrict__ w, const float* __restrict__ mu,
    const float* __restrict__ cov, float* __restrict__ ws) {
  int g = blockIdx.x * 256 + threadIdx.x;   // 0..50175
  if (g < NK) ws[OFF_LW + g] = logf(w[g]);
  int n  = g / 392;
  int dp = g - n * 392;
  int d0 = dp * 2;
  float2 cv = *(const float2*)(cov + (size_t)n * ND + d0);
  float2 mv = *(const float2*)(mu  + (size_t)n * ND + d0);
  float va[8];
  va[0] = -0.5f / cv.x;
  va[1] = mv.x / cv.x;
  va[2] = -mv.x * mv.x * 0.5f / cv.x - 0.5f * logf(cv.x);
  va[3] = 0.f;
  va[4] = -0.5f / cv.y;
  va[5] = mv.y / cv.y;
  va[6] = -mv.y * mv.y * 0.5f / cv.y - 0.5f * logf(cv.y);
  va[7] = 0.f;
  ushort hi[8], lo[8];
#pragma unroll
  for (int j = 0; j < 8; j++) {
    ushort h = f2bf(va[j]);
    hi[j] = h;
    lo[j] = f2bf(va[j] - __uint_as_float(((uint)h) << 16));
  }
  uint4 vh, vl;
  vh.x = (uint)hi[0] | ((uint)hi[1] << 16);
  vh.y = (uint)hi[2] | ((uint)hi[3] << 16);
  vh.z = (uint)hi[4] | ((uint)hi[5] << 16);
  vh.w = (uint)hi[6] | ((uint)hi[7] << 16);
  vl.x = (uint)lo[0] | ((uint)lo[1] << 16);
  vl.y = (uint)lo[2] | ((uint)lo[3] << 16);
  vl.z = (uint)lo[4] | ((uint)lo[5] << 16);
  vl.w = (uint)lo[6] | ((uint)lo[7] << 16);
  int ks = dp >> 2, lg = dp & 3, nt = n >> 4, nl = n & 15;
  int fid = ks * 8 + nt;
  int lp  = lg * 16 + nl;
  ((uint4*)(ws + OFF_BH))[fid * 64 + lp] = vh;
  ((uint4*)(ws + OFF_BL))[fid * 64 + lp] = vl;
}

// GEMM, fused A-conversion, N-split 4, KSPLIT 14:
// grid = 32 mt x 4 nh x 14 kc = 1792 blocks = 7 blocks/CU = 7 waves/SIMD
// (2x R12's TLP, same serial chain). Wave: 16 rows x 32 cols x 7 k-steps.
// Per step: batch 4 B loads + x/m (one window), convert, 6 MFMAs.
// acc layout (m89): col = lane&15, row = (lane>>4)*4 + reg.
__global__ __launch_bounds__(256, 6) void k_mm(
    const float* __restrict__ data, const float* __restrict__ mask,
    float* __restrict__ ws) {
  const short8* Bh = (const short8*)(ws + OFF_BH);
  const short8* Bl = (const short8*)(ws + OFF_BL);
  float* part = ws + OFF_PART;

  int bid = blockIdx.x;
  int mt  = bid / (NHALF * KSPLIT);
  int rem = bid % (NHALF * KSPLIT);
  int nh  = rem / KSPLIT;
  int kc  = rem % KSPLIT;
  int w   = threadIdx.x >> 6;
  int l   = threadIdx.x & 63;
  int r0  = mt * MT + w * 16;
  int rowA = r0 + (l & 15);
  int g2   = (l >> 4) << 1;     // dim offset within k-step: 0,2,4,6
  int n0   = nh * 2;            // first nt of this wave

  f32x4 acc[2];
  acc[0] = (f32x4){0.f, 0.f, 0.f, 0.f};
  acc[1] = (f32x4){0.f, 0.f, 0.f, 0.f};

  const float* dp = data + (size_t)rowA * ND + g2;
  const float* mp = mask + (size_t)rowA * ND + g2;

#pragma unroll
  for (int s = 0; s < SPK; s++) {
    int ks = kc * SPK + s;
    // ---- batch all loads for this k-step (6 independent, one window)
    const short8* bh = Bh + ((size_t)(ks * 8) + n0) * 64 + l;
    const short8* bl = Bl + ((size_t)(ks * 8) + n0) * 64 + l;
    short8 b_h0 = bh[0], b_h1 = bh[64];
    short8 b_l0 = bl[0], b_l1 = bl[64];
    float2 x = *(const float2*)(dp + ks * 8);
    float2 m = *(const float2*)(mp + ks * 8);

    // ---- A conversion (overlaps the load window)
    float mx0 = m.x * x.x, mq0 = mx0 * x.x;
    float mx1 = m.y * x.y, mq1 = mx1 * x.y;
    ushort h_q0 = f2bf(mq0), h_x0 = f2bf(mx0);
    ushort h_q1 = f2bf(mq1), h_x1 = f2bf(mx1);
    ushort h_m0 = (ushort)(__float_as_uint(m.x) >> 16);  // exact: m in {0,1}
    ushort h_m1 = (ushort)(__float_as_uint(m.y) >> 16);
    float r_q0 = mq0 - __uint_as_float(((uint)h_q0) << 16);
    float r_x0 = mx0 - __uint_as_float(((uint)h_x0) << 16);
    float r_q1 = mq1 - __uint_as_float(((uint)h_q1) << 16);
    float r_x1 = mx1 - __uint_as_float(((uint)h_x1) << 16);

    short8 a_h, a_l;
    a_h[0] = (short)h_q0;       a_h[1] = (short)h_x0;
    a_h[2] = (short)h_m0;       a_h[3] = 0;
    a_h[4] = (short)h_q1;       a_h[5] = (short)h_x1;
    a_h[6] = (short)h_m1;       a_h[7] = 0;
    a_l[0] = (short)f2bf(r_q0); a_l[1] = (short)f2bf(r_x0);
    a_l[2] = 0;                 a_l[3] = 0;
    a_l[4] = (short)f2bf(r_q1); a_l[5] = (short)f2bf(r_x1);
    a_l[6] = 0;                 a_l[7] = 0;

    // ---- 6 MFMAs
    acc[0] = __builtin_amdgcn_mfma_f32_16x16x32_bf16(a_h, b_h0, acc[0], 0, 0, 0);
    acc[0] = __builtin_amdgcn_mfma_f32_16x16x32_bf16(a_h, b_l0, acc[0], 0, 0, 0);
    acc[0] = __builtin_amdgcn_mfma_f32_16x16x32_bf16(a_l, b_h0, acc[0], 0, 0, 0);
    acc[1] = __builtin_amdgcn_mfma_f32_16x16x32_bf16(a_h, b_h1, acc[1], 0, 0, 0);
    acc[1] = __builtin_amdgcn_mfma_f32_16x16x32_bf16(a_h, b_l1, acc[1], 0, 0, 0);
    acc[1] = __builtin_amdgcn_mfma_f32_16x16x32_bf16(a_l, b_h1, acc[1], 0, 0, 0);
  }

#pragma unroll
  for (int ntl = 0; ntl < 2; ntl++)
#pragma unroll
    for (int r = 0; r < 4; r++) {
      int grow = r0 + ((l >> 4) << 2) + r;
      part[((size_t)kc * NB + grow) * NK + (n0 + ntl) * 16 + (l & 15)] = acc[ntl][r];
    }
}

// 1 row per wave, float2 per lane -> 2048 waves (2/SIMD, 2x R17's TLP).
// Reduce KSPLIT partials, +log w, NaN fix, LSE with the reference's
// per-term +1e-8 (2e-8 per lane), exp.
__global__ __launch_bounds__(256) void k_final(
    const float* __restrict__ ws, float* __restrict__ out) {
  const float2* lw2   = (const float2*)(ws + OFF_LW);
  const float2* part2 = (const float2*)(ws + OFF_PART);
  int lane = threadIdx.x & 63;
  int wv   = threadIdx.x >> 6;
  int b = blockIdx.x * 4 + wv;

  float2 s = make_float2(0.f, 0.f);
#pragma unroll
  for (int sp = 0; sp < KSPLIT; sp++) {
    float2 v = part2[((size_t)sp * NB + b) * 64 + lane];
    s.x += v.x; s.y += v.y;
  }
  float2 lv = lw2[lane];
  s.x += lv.x; s.y += lv.y;
  if (isnan(s.x)) s.x = 0.f;
  if (isnan(s.y)) s.y = 0.f;

  float mx = fmaxf(s.x, s.y);
#pragma unroll
  for (int off = 32; off; off >>= 1) mx = fmaxf(mx, __shfl_xor(mx, off));
  float sum = expf(s.x - mx) + expf(s.y - mx) + 2e-8f;
#pragma unroll
  for (int off = 32; off; off >>= 1) sum += __shfl_xor(sum, off);
  float lse = logf(sum) + mx;
  float2 o = make_float2(expf(s.x - lse), expf(s.y - lse));
  ((float2*)out)[(size_t)b * 64 + lane] = o;
}

extern "C" void kernel_launch(void* const* d_in, const int* in_sizes, int n_in,
                              void* d_out, int out_size, void* d_ws, size_t ws_size,
                              hipStream_t stream) {
  const float* data = (const float*)d_in[0];
  const float* mask = (const float*)d_in[1];
  const float* wts  = (const float*)d_in[2];
  const float* mu   = (const float*)d_in[3];
  const float* cov  = (const float*)d_in[4];
  float* ws  = (float*)d_ws;
  float* out = (float*)d_out;

  k_prep<<<196, 256, 0, stream>>>(wts, mu, cov, ws);
  k_mm<<<32 * NHALF * KSPLIT, 256, 0, stream>>>(data, mask, ws);
  k_final<<<NB / 4, 256, 0, stream>>>(ws, out);
}

// Round 20
// 23.812 us; speedup vs baseline: 1.6317x; 1.3639x over previous
//
#include <hip/hip_runtime.h>
#include <math.h>

#define NB 2048
#define ND 784
#define NK 128
#define NSTEP 98           // K = 4d+c -> 3136 = 98 k-steps of 32
#define KSPLIT 14          // K-chunks -> partials
#define SPK 7              // k-steps per chunk
#define MT 128             // rows per k_mm block (8 waves x 16 rows)
#define NHALF 2            // N-split: block does 4 nt = 64 cols

typedef __attribute__((ext_vector_type(8))) short short8;
typedef __attribute__((ext_vector_type(4))) float f32x4;

// ws float offsets: only partials now.
#define OFF_PART 0
#define N_PART   (KSPLIT * NB * NK)       // 3,670,016 floats (14.7 MB)

__device__ inline ushort f2bf(float f) {   // round-to-nearest-even f32->bf16
  uint u = __float_as_uint(f);
  return (ushort)((u + 0x7FFFu + ((u >> 16) & 1u)) >> 16);
}

// Fused B-prep + GEMM. Grid = 16 mt x 2 nh x 14 kc = 448 blocks, 512 threads
// (8 waves), 2 blocks/CU (LDS 57344 B) -> 16 waves/CU = 3.5+ waves/SIMD avg.
// Phase A: cooperative B-slice build into LDS (coalesced cov/mu float2 reads,
//   bit-identical table math, fragment-linear layout).
// Phase B: R15-proven loop: x/m prefetch + A-preconvert, then per k-step
//   {8 conflict-free ds_read_b128 -> 12 MFMAs}.
// acc layout (m89): col = lane&15, row = (lane>>4)*4 + reg.
__global__ __launch_bounds__(512, 4) void k_mm(
    const float* __restrict__ data, const float* __restrict__ mask,
    const float* __restrict__ mu, const float* __restrict__ cov,
    float* __restrict__ ws) {
  __shared__ uint4 BhL[SPK * 4 * 64];   // 28672 B
  __shared__ uint4 BlL[SPK * 4 * 64];   // 28672 B

  float* part = ws + OFF_PART;

  int bid = blockIdx.x;
  int mt  = bid / (NHALF * KSPLIT);
  int rem = bid % (NHALF * KSPLIT);
  int nh  = rem / KSPLIT;
  int kc  = rem % KSPLIT;
  int w   = threadIdx.x >> 6;
  int l   = threadIdx.x & 63;
  int r0  = mt * MT + w * 16;
  int rowA = r0 + (l & 15);
  int g2   = (l >> 4) << 1;     // dim offset within k-step: 0,2,4,6
  int n0   = nh * 4;            // block's first nt

  const float* dp = data + (size_t)rowA * ND + g2;
  const float* mp = mask + (size_t)rowA * ND + g2;

  // ---- issue x/m prefetch first (in flight during B staging)
  float2 xs[SPK], ms[SPK];
#pragma unroll
  for (int s = 0; s < SPK; s++) {
    int ks = kc * SPK + s;
    xs[s] = *(const float2*)(dp + ks * 8);
    ms[s] = *(const float2*)(mp + ks * 8);
  }

  // ---- Phase A: build B-slice in LDS.
  // Items: 64 cols x 28 dim-pairs = 1792; thread t handles t, t+512, ...
  {
    int d0 = kc * 56;            // first dim of this kc chunk
    int nb = nh * 64;            // first col of this nh half
#pragma unroll
    for (int i = 0; i < 4; i++) {
      int idx = threadIdx.x + i * 512;
      if (idx < 1792) {
        int n  = idx / 28;       // local col 0..63
        int dl = idx - n * 28;   // local dim-pair 0..27
        int d  = d0 + 2 * dl;
        float2 cv = *(const float2*)(cov + (size_t)(nb + n) * ND + d);
        float2 mv = *(const float2*)(mu  + (size_t)(nb + n) * ND + d);
        float va[8];
        va[0] = -0.5f / cv.x;
        va[1] = mv.x / cv.x;
        va[2] = -mv.x * mv.x * 0.5f / cv.x - 0.5f * logf(cv.x);
        va[3] = 0.f;
        va[4] = -0.5f / cv.y;
        va[5] = mv.y / cv.y;
        va[6] = -mv.y * mv.y * 0.5f / cv.y - 0.5f * logf(cv.y);
        va[7] = 0.f;
        ushort hi[8], lo[8];
#pragma unroll
        for (int j = 0; j < 8; j++) {
          ushort h = f2bf(va[j]);
          hi[j] = h;
          lo[j] = f2bf(va[j] - __uint_as_float(((uint)h) << 16));
        }
        uint4 vh, vl;
        vh.x = (uint)hi[0] | ((uint)hi[1] << 16);
        vh.y = (uint)hi[2] | ((uint)hi[3] << 16);
        vh.z = (uint)hi[4] | ((uint)hi[5] << 16);
        vh.w = (uint)hi[6] | ((uint)hi[7] << 16);
        vl.x = (uint)lo[0] | ((uint)lo[1] << 16);
        vl.y = (uint)lo[2] | ((uint)lo[3] << 16);
        vl.z = (uint)lo[4] | ((uint)lo[5] << 16);
        vl.w = (uint)lo[6] | ((uint)lo[7] << 16);
        int ks_l = dl >> 2, lg = dl & 3, ntl = n >> 4, nl = n & 15;
        int fl = ks_l * 4 + ntl;
        int lp = lg * 16 + nl;
        BhL[fl * 64 + lp] = vh;
        BlL[fl * 64 + lp] = vl;
      }
    }
  }

  // ---- A-preconvert (off the k-loop critical path; overlaps LDS staging tail)
  short8 ah[SPK], al[SPK];
#pragma unroll
  for (int s = 0; s < SPK; s++) {
    float2 x = xs[s], m = ms[s];
    float mx0 = m.x * x.x, mq0 = mx0 * x.x;
    float mx1 = m.y * x.y, mq1 = mx1 * x.y;
    ushort h_q0 = f2bf(mq0), h_x0 = f2bf(mx0);
    ushort h_q1 = f2bf(mq1), h_x1 = f2bf(mx1);
    ushort h_m0 = (ushort)(__float_as_uint(m.x) >> 16);  // exact: m in {0,1}
    ushort h_m1 = (ushort)(__float_as_uint(m.y) >> 16);
    float r_q0 = mq0 - __uint_as_float(((uint)h_q0) << 16);
    float r_x0 = mx0 - __uint_as_float(((uint)h_x0) << 16);
    float r_q1 = mq1 - __uint_as_float(((uint)h_q1) << 16);
    float r_x1 = mx1 - __uint_as_float(((uint)h_x1) << 16);
    ah[s][0] = (short)h_q0;       ah[s][1] = (short)h_x0;
    ah[s][2] = (short)h_m0;       ah[s][3] = 0;
    ah[s][4] = (short)h_q1;       ah[s][5] = (short)h_x1;
    ah[s][6] = (short)h_m1;       ah[s][7] = 0;
    al[s][0] = (short)f2bf(r_q0); al[s][1] = (short)f2bf(r_x0);
    al[s][2] = 0;                 al[s][3] = 0;
    al[s][4] = (short)f2bf(r_q1); al[s][5] = (short)f2bf(r_x1);
    al[s][6] = 0;                 al[s][7] = 0;
  }

  __syncthreads();

  f32x4 acc[4];
#pragma unroll
  for (int i = 0; i < 4; i++) acc[i] = (f32x4){0.f, 0.f, 0.f, 0.f};

  const short8* BhS = (const short8*)BhL;
  const short8* BlS = (const short8*)BlL;

#pragma unroll
  for (int s = 0; s < SPK; s++) {
    // 8 conflict-free ds_read_b128 (consecutive lanes 16B apart)
    short8 b_h0 = BhS[(s * 4 + 0) * 64 + l];
    short8 b_h1 = BhS[(s * 4 + 1) * 64 + l];
    short8 b_h2 = BhS[(s * 4 + 2) * 64 + l];
    short8 b_h3 = BhS[(s * 4 + 3) * 64 + l];
    short8 b_l0 = BlS[(s * 4 + 0) * 64 + l];
    short8 b_l1 = BlS[(s * 4 + 1) * 64 + l];
    short8 b_l2 = BlS[(s * 4 + 2) * 64 + l];
    short8 b_l3 = BlS[(s * 4 + 3) * 64 + l];

    acc[0] = __builtin_amdgcn_mfma_f32_16x16x32_bf16(ah[s], b_h0, acc[0], 0, 0, 0);
    acc[0] = __builtin_amdgcn_mfma_f32_16x16x32_bf16(ah[s], b_l0, acc[0], 0, 0, 0);
    acc[0] = __builtin_amdgcn_mfma_f32_16x16x32_bf16(al[s], b_h0, acc[0], 0, 0, 0);
    acc[1] = __builtin_amdgcn_mfma_f32_16x16x32_bf16(ah[s], b_h1, acc[1], 0, 0, 0);
    acc[1] = __builtin_amdgcn_mfma_f32_16x16x32_bf16(ah[s], b_l1, acc[1], 0, 0, 0);
    acc[1] = __builtin_amdgcn_mfma_f32_16x16x32_bf16(al[s], b_h1, acc[1], 0, 0, 0);
    acc[2] = __builtin_amdgcn_mfma_f32_16x16x32_bf16(ah[s], b_h2, acc[2], 0, 0, 0);
    acc[2] = __builtin_amdgcn_mfma_f32_16x16x32_bf16(ah[s], b_l2, acc[2], 0, 0, 0);
    acc[2] = __builtin_amdgcn_mfma_f32_16x16x32_bf16(al[s], b_h2, acc[2], 0, 0, 0);
    acc[3] = __builtin_amdgcn_mfma_f32_16x16x32_bf16(ah[s], b_h3, acc[3], 0, 0, 0);
    acc[3] = __builtin_amdgcn_mfma_f32_16x16x32_bf16(ah[s], b_l3, acc[3], 0, 0, 0);
    acc[3] = __builtin_amdgcn_mfma_f32_16x16x32_bf16(al[s], b_h3, acc[3], 0, 0, 0);
  }

#pragma unroll
  for (int ntl = 0; ntl < 4; ntl++)
#pragma unroll
    for (int r = 0; r < 4; r++) {
      int grow = r0 + ((l >> 4) << 2) + r;
      part[((size_t)kc * NB + grow) * NK + (n0 + ntl) * 16 + (l & 15)] = acc[ntl][r];
    }
}

// 2 rows per wave, float4 per lane (k-quad). Reduce KSPLIT partials,
// +log w (computed inline), NaN fix, LSE with the reference's per-term
// +1e-8 (4e-8 per lane), exp.
__global__ __launch_bounds__(256) void k_final(
    const float* __restrict__ wts, const float* __restrict__ ws,
    float* __restrict__ out) {
  const float4* part4 = (const float4*)(ws + OFF_PART);
  int lane = threadIdx.x & 63;
  int wv   = threadIdx.x >> 6;
  int half = lane >> 5;
  int lk   = lane & 31;
  int b = blockIdx.x * 8 + wv * 2 + half;

  float4 s = make_float4(0.f, 0.f, 0.f, 0.f);
#pragma unroll
  for (int sp = 0; sp < KSPLIT; sp++) {
    float4 v = part4[((size_t)sp * NB + b) * 32 + lk];
    s.x += v.x; s.y += v.y; s.z += v.z; s.w += v.w;
  }
  float4 wv4 = *(const float4*)(wts + lk * 4);
  s.x += logf(wv4.x); s.y += logf(wv4.y);
  s.z += logf(wv4.z); s.w += logf(wv4.w);
  if (isnan(s.x)) s.x = 0.f;
  if (isnan(s.y)) s.y = 0.f;
  if (isnan(s.z)) s.z = 0.f;
  if (isnan(s.w)) s.w = 0.f;

  float mx = fmaxf(fmaxf(s.x, s.y), fmaxf(s.z, s.w));
#pragma unroll
  for (int off = 16; off; off >>= 1) mx = fmaxf(mx, __shfl_xor(mx, off));
  float sum = expf(s.x - mx) + expf(s.y - mx) + expf(s.z - mx) + expf(s.w - mx) + 4e-8f;
#pragma unroll
  for (int off = 16; off; off >>= 1) sum += __shfl_xor(sum, off);
  float lse = logf(sum) + mx;
  float4 o = make_float4(expf(s.x - lse), expf(s.y - lse),
                         expf(s.z - lse), expf(s.w - lse));
  ((float4*)out)[(size_t)b * 32 + lk] = o;
}

extern "C" void kernel_launch(void* const* d_in, const int* in_sizes, int n_in,
                              void* d_out, int out_size, void* d_ws, size_t ws_size,
                              hipStream_t stream) {
  const float* data = (const float*)d_in[0];
  const float* mask = (const float*)d_in[1];
  const float* wts  = (const float*)d_in[2];
  const float* mu   = (const float*)d_in[3];
  const float* cov  = (const float*)d_in[4];
  float* ws  = (float*)d_ws;
  float* out = (float*)d_out;

  k_mm<<<(NB / MT) * NHALF * KSPLIT, 512, 0, stream>>>(data, mask, mu, cov, ws);
  k_final<<<NB / 8, 256, 0, stream>>>(wts, ws, out);
}